// Round 10
// baseline (596.883 us; speedup 1.0000x reference)
//
#include <hip/hip_runtime.h>
#include <cstdint>
#include <cstddef>

#define H      640
#define RH     256
#define NE     5
#define NA     40          // NE * rank
#define NTOK   32768
#define SCAL   2.0f        // alpha/rank = 16/8
#define BK     16
#define BM     64          // tokens/block -> grid 512 = 2 blocks/CU
#define NT     (H / BK)    // 40 K-tiles

__device__ __forceinline__ float4 ld4(const float* p) {
    return *reinterpret_cast<const float4*>(p);
}

// async global->LDS, 16B/lane: dest = wave-uniform base + lane*16
__device__ __forceinline__ void gload16(const float* g, float* lds_base) {
    __builtin_amdgcn_global_load_lds(
        (const __attribute__((address_space(1))) void*)g,
        (__attribute__((address_space(3))) void*)lds_base, 16, 0, 0);
}

// ---------------------------------------------------------------------------
// Kernel 1: router (x@W1 -> silu -> @W2 -> softmax -> top2) + low = x@A.
// 8x8 register tile: 256 thr, tm=tid>>5 owns tokens 8tm..8tm+7, tn=tid&31
// owns cols {tn*4..+3} u {128+tn*4..+3} (+2 A-cols tn*2,tn*2+1, 64-padded).
// Per k per thread: 2 broadcast xa b128 (xs transposed [k][tok], 2 distinct
// addrs/wave ~1cyc) + 2 bb b128 (4-way spread = 4cyc, optimal) + 1 lb b64 +
// 80 FMA -> LDS pipe ~12cyc vs VALU 160cyc per wave per k: LDS now at 30%
// of balance (R3's 2x16 tile had LDS-pipe = 100% = the real wall).
// Simple sync-stage-sync loop; W1 via global_load_lds; grid 512 = 2 blocks/
// CU, __launch_bounds__(256,4) caps VGPR 128 (acc 80 regs, R7 measured 84
// for same-size acc -> no spill expected). Compute 5120 cyc/SIMD/tile vs
// ~500cyc stage stall, alternate block covers barriers.
// ---------------------------------------------------------------------------
__global__ __launch_bounds__(256, 4)
void k_router(const float* __restrict__ x, const float* __restrict__ W1,
              const float* __restrict__ b1v, const float* __restrict__ W2,
              const float* __restrict__ b2v, const float* __restrict__ A,
              float* __restrict__ route_c, int* __restrict__ route_idx)
{
    __shared__ float ws[BK][RH];          // 16 KB (epilogue: aliased by low)
    __shared__ float xs[BK][BM];          // 4 KB, transposed [k][tok]
    __shared__ float as_[BK][64];         // 4 KB (cols 40..63 garbage, unused)
    __shared__ float w2s[RH * NE];        // 5 KB
    __shared__ float b1s[RH];             // 1 KB
    __shared__ float logit_lds[BM][8];    // 2 KB
    float (*low_lds)[NA] = reinterpret_cast<float (*)[NA]>(&ws[0][0]); // 10.2KB

    const int tid  = threadIdx.x;
    const int row0 = blockIdx.x * BM;
    const int tm   = tid >> 5;           // 0..7
    const int tn   = tid & 31;           // 0..31
    const int lane = tid & 63;
    const int wv   = tid >> 6;           // 0..3

    // staging maps
    const int tok_s = tid & 63;          // x: token
    const int kg_s  = tid >> 6;          // x: k-group (0..3)
    const float* xsrc = x + (size_t)(row0 + tok_s) * H + kg_s * 4;
    const int arow = tid / 10, ac4 = tid % 10;    // A: 160 f4 (tid<160)
    const int ae = ac4 >> 1, ar0 = (ac4 & 1) * 4;
    const float* asrc = A + ((size_t)ae * H + arow) * 8 + ar0;

    for (int i = tid; i < RH * NE; i += 256) w2s[i] = W2[i];
    if (tid < RH) b1s[tid] = b1v[tid];

    float acc[8][8];
    #pragma unroll
    for (int j = 0; j < 8; j++)
        #pragma unroll
        for (int c = 0; c < 8; c++) acc[j][c] = 0.f;
    float accl[8][2];
    #pragma unroll
    for (int j = 0; j < 8; j++) { accl[j][0] = 0.f; accl[j][1] = 0.f; }

    for (int t = 0; t < NT; ++t) {
        const int k0 = t * BK;
        __syncthreads();                 // waves done reading tile t-1
        // W1 tile [16][256] via async global->LDS (1 KB row per wave-instr)
        #pragma unroll
        for (int i = 0; i < 4; i++)
            gload16(W1 + (size_t)(k0 + wv * 4 + i) * RH + lane * 4,
                    &ws[wv * 4 + i][0]);
        // x tile transposed: ld4 of 4 k, 4 scalar ds_writes (2-way banks)
        {
            float4 xv = ld4(xsrc + k0);
            xs[kg_s * 4 + 0][tok_s] = xv.x;
            xs[kg_s * 4 + 1][tok_s] = xv.y;
            xs[kg_s * 4 + 2][tok_s] = xv.z;
            xs[kg_s * 4 + 3][tok_s] = xv.w;
        }
        // A tile [16][40 real]
        if (tid < 160)
            *reinterpret_cast<float4*>(&as_[arow][ac4 * 4]) =
                ld4(asrc + (size_t)k0 * 8);
        __syncthreads();                 // drains vmcnt (gload) + lgkm

        #pragma unroll
        for (int kk = 0; kk < BK; kk++) {
            float xa[8];
            *reinterpret_cast<float4*>(&xa[0]) =
                *reinterpret_cast<const float4*>(&xs[kk][8 * tm]);
            *reinterpret_cast<float4*>(&xa[4]) =
                *reinterpret_cast<const float4*>(&xs[kk][8 * tm + 4]);
            float bb[8];
            *reinterpret_cast<float4*>(&bb[0]) =
                *reinterpret_cast<const float4*>(&ws[kk][tn * 4]);
            *reinterpret_cast<float4*>(&bb[4]) =
                *reinterpret_cast<const float4*>(&ws[kk][128 + tn * 4]);
            float lb0 = as_[kk][tn * 2];
            float lb1 = as_[kk][tn * 2 + 1];
            #pragma unroll
            for (int j = 0; j < 8; j++) {
                #pragma unroll
                for (int c = 0; c < 8; c++)
                    acc[j][c] = fmaf(xa[j], bb[c], acc[j][c]);
                accl[j][0] = fmaf(xa[j], lb0, accl[j][0]);
                accl[j][1] = fmaf(xa[j], lb1, accl[j][1]);
            }
        }
    }

    __syncthreads();   // K-loop reads done; ws region now reused as low_lds

    // publish low values: thread (tm,tn<20) owns tokens 8tm..+7, acols 2tn,2tn+1
    if (tn < 20) {
        #pragma unroll
        for (int j = 0; j < 8; j++) {
            low_lds[8 * tm + j][tn * 2]     = accl[j][0];
            low_lds[8 * tm + j][tn * 2 + 1] = accl[j][1];
        }
    }

    // silu + b1, partial logits over this thread's 8 cols
    float part[8][5];
    #pragma unroll
    for (int j = 0; j < 8; j++)
        #pragma unroll
        for (int e = 0; e < 5; e++) part[j][e] = 0.f;

    #pragma unroll
    for (int c8 = 0; c8 < 8; c8++) {
        const int col = (c8 < 4) ? (tn * 4 + c8) : (128 + tn * 4 + (c8 - 4));
        float bbias = b1s[col];
        float w2r[5];
        #pragma unroll
        for (int e = 0; e < 5; e++) w2r[e] = w2s[col * 5 + e];
        #pragma unroll
        for (int j = 0; j < 8; j++) {
            float v = acc[j][c8] + bbias;
            float s = __fdividef(v, 1.f + __expf(-v));   // silu
            #pragma unroll
            for (int e = 0; e < 5; e++) part[j][e] = fmaf(s, w2r[e], part[j][e]);
        }
    }

    // reduce partials across the 32 tn-lanes (xor<32 stays in each half-wave)
    #pragma unroll
    for (int j = 0; j < 8; j++)
        #pragma unroll
        for (int e = 0; e < 5; e++) {
            float v = part[j][e];
            v += __shfl_xor(v, 16);
            v += __shfl_xor(v, 8);
            v += __shfl_xor(v, 4);
            v += __shfl_xor(v, 2);
            v += __shfl_xor(v, 1);
            part[j][e] = v;
        }

    if (tn == 0) {
        #pragma unroll
        for (int j = 0; j < 8; j++)
            #pragma unroll
            for (int e = 0; e < 5; e++) logit_lds[8 * tm + j][e] = part[j][e];
    }
    __syncthreads();

    // one thread per token: top-2 + route_c write
    if (tid < BM) {
        const int tk = tid;
        float l0 = logit_lds[tk][0] + b2v[0];
        float l1 = logit_lds[tk][1] + b2v[1];
        float l2 = logit_lds[tk][2] + b2v[2];
        float l3 = logit_lds[tk][3] + b2v[3];
        float l4 = logit_lds[tk][4] + b2v[4];
        int   i0 = 0;  float m0 = l0;
        int   i1 = -1; float m1 = -3.4e38f;
        if (l1 > m0) { m1 = m0; i1 = i0; m0 = l1; i0 = 1; } else if (l1 > m1) { m1 = l1; i1 = 1; }
        if (l2 > m0) { m1 = m0; i1 = i0; m0 = l2; i0 = 2; } else if (l2 > m1) { m1 = l2; i1 = 2; }
        if (l3 > m0) { m1 = m0; i1 = i0; m0 = l3; i0 = 3; } else if (l3 > m1) { m1 = l3; i1 = 3; }
        if (l4 > m0) { m1 = m0; i1 = i0; m0 = l4; i0 = 4; } else if (l4 > m1) { m1 = l4; i1 = 4; }
        float w1r = __expf(m1 - m0);
        float inv = __fdividef(1.f, 1.f + w1r);
        float c0 = inv * SCAL;
        float c1 = w1r * inv * SCAL;
        int gt = row0 + tk;
        #pragma unroll
        for (int r4 = 0; r4 < 2; r4++) {
            float4 v0 = ld4(&low_lds[tk][i0 * 8 + r4 * 4]);
            v0.x *= c0; v0.y *= c0; v0.z *= c0; v0.w *= c0;
            *reinterpret_cast<float4*>(&route_c[(size_t)gt * 16 + r4 * 4]) = v0;
            float4 v1 = ld4(&low_lds[tk][i1 * 8 + r4 * 4]);
            v1.x *= c1; v1.y *= c1; v1.z *= c1; v1.w *= c1;
            *reinterpret_cast<float4*>(&route_c[(size_t)gt * 16 + 8 + r4 * 4]) = v1;
        }
        route_idx[gt * 2 + 0] = i0;
        route_idx[gt * 2 + 1] = i1;
    }
}

// ---------------------------------------------------------------------------
// Kernel 2: out[t] = base[t] + sum_j c[t][j] * Bm_row[idx_j][:]
// All of Bm (40x640 f32 = 102.4 KB) staged in LDS. 512 thr (8 waves), one
// wave per token at a time; grid = 256 blocks * 128 tokens. ~27 us = at the
// 168 MB HBM floor (base+out) -- unchanged.
// ---------------------------------------------------------------------------
__global__ __launch_bounds__(512)
void k_combine(const float* __restrict__ base, const float* __restrict__ Bm,
               const float* __restrict__ route_c, const int* __restrict__ route_idx,
               float* __restrict__ out)
{
    __shared__ float bs[NA][H];
    const int tid = threadIdx.x;
    for (int i4 = tid; i4 < NA * H / 4; i4 += 512)
        reinterpret_cast<float4*>(&bs[0][0])[i4] = reinterpret_cast<const float4*>(Bm)[i4];
    __syncthreads();

    const int w    = tid >> 6;
    const int lane = tid & 63;

    for (int it = 0; it < 16; it++) {
        int t = blockIdx.x * 128 + w * 16 + it;
        t = __builtin_amdgcn_readfirstlane(t);
        const int e0 = route_idx[t * 2 + 0];
        const int e1 = route_idx[t * 2 + 1];
        float cc[16];
        #pragma unroll
        for (int q = 0; q < 4; q++)
            *reinterpret_cast<float4*>(&cc[q * 4]) = ld4(route_c + (size_t)t * 16 + q * 4);

        const float* brow0 = &bs[e0 * 8][0];
        const float* brow1 = &bs[e1 * 8][0];
        const float* bp = base + (size_t)t * H;
        float*       op = out  + (size_t)t * H;

        #pragma unroll
        for (int i = 0; i < 2; i++) {
            int h = i * 256 + lane * 4;
            float4 a = ld4(bp + h);
            #pragma unroll
            for (int j = 0; j < 8; j++) {
                float4 bv = *reinterpret_cast<const float4*>(brow0 + j * H + h);
                a.x = fmaf(cc[j], bv.x, a.x); a.y = fmaf(cc[j], bv.y, a.y);
                a.z = fmaf(cc[j], bv.z, a.z); a.w = fmaf(cc[j], bv.w, a.w);
            }
            #pragma unroll
            for (int j = 0; j < 8; j++) {
                float4 bv = *reinterpret_cast<const float4*>(brow1 + j * H + h);
                a.x = fmaf(cc[8 + j], bv.x, a.x); a.y = fmaf(cc[8 + j], bv.y, a.y);
                a.z = fmaf(cc[8 + j], bv.z, a.z); a.w = fmaf(cc[8 + j], bv.w, a.w);
            }
            *reinterpret_cast<float4*>(op + h) = a;
        }
        {
            int h = 512 + lane * 2;
            float2 a = *reinterpret_cast<const float2*>(bp + h);
            #pragma unroll
            for (int j = 0; j < 8; j++) {
                float2 bv = *reinterpret_cast<const float2*>(brow0 + j * H + h);
                a.x = fmaf(cc[j], bv.x, a.x); a.y = fmaf(cc[j], bv.y, a.y);
            }
            #pragma unroll
            for (int j = 0; j < 8; j++) {
                float2 bv = *reinterpret_cast<const float2*>(brow1 + j * H + h);
                a.x = fmaf(cc[8 + j], bv.x, a.x); a.y = fmaf(cc[8 + j], bv.y, a.y);
            }
            *reinterpret_cast<float2*>(op + h) = a;
        }
    }
}

extern "C" void kernel_launch(void* const* d_in, const int* in_sizes, int n_in,
                              void* d_out, int out_size, void* d_ws, size_t ws_size,
                              hipStream_t stream)
{
    const float* x  = (const float*)d_in[0];
    const float* bo = (const float*)d_in[1];
    const float* W1 = (const float*)d_in[2];
    const float* b1 = (const float*)d_in[3];
    const float* W2 = (const float*)d_in[4];
    const float* b2 = (const float*)d_in[5];
    const float* A  = (const float*)d_in[6];
    const float* Bm = (const float*)d_in[7];
    float* out = (float*)d_out;

    float* route_c   = (float*)d_ws;                                   // 32768*16 f32 = 2 MB
    int*   route_idx = (int*)((char*)d_ws + (size_t)NTOK * 16 * 4);    // 32768*2 i32 = 256 KB

    k_router<<<dim3(NTOK / BM), dim3(256), 0, stream>>>(
        x, W1, b1, W2, b2, A, route_c, route_idx);
    k_combine<<<dim3(256), dim3(512), 0, stream>>>(
        bo, Bm, route_c, route_idx, out);
}